// Round 1
// baseline (2167.424 us; speedup 1.0000x reference)
//
#include <hip/hip_runtime.h>
#include <math.h>

#define CCH   768
#define HDIM  180
#define WDIM  360
#define NY    91                 // kept W-frequency modes (H//2+1 of 180)
#define NMODE (HDIM*NY)          // 16380 modes per channel
#define BSZ   96                 // channels per block-diagonal block
#define LAM   0.01f
#define ORTHO 0.003928371006591930f   // 1/sqrt(180*360)

// ---------------------------------------------------------------------------
// Stage A: forward real DFT along W (360 real -> 91 complex), ortho scale folded.
// One block = 32 consecutive (c,h) rows. F layout: planar [c][h][y] (= [row][y]).
__global__ __launch_bounds__(256) void kA(const float* __restrict__ x,
                                          float* __restrict__ fre,
                                          float* __restrict__ fim) {
    __shared__ __align__(16) float xs[WDIM][36];   // [w][row-in-block], pad 32->36
    __shared__ float2 tw[WDIM];
    const int tid  = threadIdx.x;
    const int base = blockIdx.x * (32 * WDIM);
    for (int i = tid; i < 32 * WDIM; i += 256) {
        const int r = i / WDIM;
        const int w = i - r * WDIM;
        xs[w][r] = x[base + i];
    }
    for (int j = tid; j < WDIM; j += 256) {
        float sv, cv;
        sincosf(0.017453292519943295f * (float)j, &sv, &cv);   // 2*pi*j/360
        tw[j] = make_float2(cv, sv);
    }
    __syncthreads();
    const int row0 = blockIdx.x * 32;
    for (int t = tid; t < NY * 8; t += 256) {
        const int y = t >> 3;
        const int g = (t & 7) << 2;          // first of 4 rows handled
        float ar0=0.f,ar1=0.f,ar2=0.f,ar3=0.f;
        float ai0=0.f,ai1=0.f,ai2=0.f,ai3=0.f;
        int idx = 0;                          // (w*y) mod 360, incremental
        for (int w = 0; w < WDIM; ++w) {
            const float2 cs = tw[idx];
            idx += y; if (idx >= WDIM) idx -= WDIM;
            const float4 xv = *(const float4*)&xs[w][g];
            // e^{-i theta}: re += x*cos ; im -= x*sin
            ar0 = fmaf(xv.x, cs.x, ar0); ai0 = fmaf(-xv.x, cs.y, ai0);
            ar1 = fmaf(xv.y, cs.x, ar1); ai1 = fmaf(-xv.y, cs.y, ai1);
            ar2 = fmaf(xv.z, cs.x, ar2); ai2 = fmaf(-xv.z, cs.y, ai2);
            ar3 = fmaf(xv.w, cs.x, ar3); ai3 = fmaf(-xv.w, cs.y, ai3);
        }
        int oa = (row0 + g) * NY + y;
        fre[oa] = ar0 * ORTHO; fim[oa] = ai0 * ORTHO; oa += NY;
        fre[oa] = ar1 * ORTHO; fim[oa] = ai1 * ORTHO; oa += NY;
        fre[oa] = ar2 * ORTHO; fim[oa] = ai2 * ORTHO; oa += NY;
        fre[oa] = ar3 * ORTHO; fim[oa] = ai3 * ORTHO;
    }
}

// ---------------------------------------------------------------------------
// Stages B/D: 180-point complex DFT along H, in place. One block = (c, y-tile of 32).
// INV=0: e^{-i t}, INV=1: e^{+i t}. No scaling (ortho folded into kA/kE).
template<int INV>
__global__ __launch_bounds__(256) void kH(float* __restrict__ fre,
                                          float* __restrict__ fim) {
    __shared__ __align__(16) float inr[HDIM][32], ini[HDIM][32];
    __shared__ float2 tw[HDIM];
    const int tid   = threadIdx.x;
    const int c     = blockIdx.x;
    const int y0    = blockIdx.y * 32;
    const int ylen  = (NY - y0 < 32) ? (NY - y0) : 32;
    const int cbase = c * NMODE;
    for (int t = tid; t < HDIM * 32; t += 256) {
        const int hh = t >> 5;
        const int yy = t & 31;
        float vr = 0.f, vi = 0.f;
        if (yy < ylen) {
            const int a = cbase + hh * NY + y0 + yy;
            vr = fre[a]; vi = fim[a];
        }
        inr[hh][yy] = vr; ini[hh][yy] = vi;
    }
    for (int j = tid; j < HDIM; j += 256) {
        float sv, cv;
        sincosf(0.034906585039886591f * (float)j, &sv, &cv);   // 2*pi*j/180
        tw[j] = make_float2(cv, sv);
    }
    __syncthreads();
    for (int t = tid; t < HDIM * 8; t += 256) {
        const int h = t >> 3;
        const int g = (t & 7) << 2;          // y offset within tile (4 at a time)
        float ar0=0.f,ar1=0.f,ar2=0.f,ar3=0.f;
        float ai0=0.f,ai1=0.f,ai2=0.f,ai3=0.f;
        int idx = 0;                          // (hh*h) mod 180, incremental
        for (int hh = 0; hh < HDIM; ++hh) {
            const float2 cs = tw[idx];
            idx += h; if (idx >= HDIM) idx -= HDIM;
            const float4 xr = *(const float4*)&inr[hh][g];
            const float4 xi = *(const float4*)&ini[hh][g];
            if (!INV) {   // re += c*Xr + s*Xi ; im += c*Xi - s*Xr
                ar0 = fmaf(cs.x, xr.x, fmaf( cs.y, xi.x, ar0));
                ai0 = fmaf(cs.x, xi.x, fmaf(-cs.y, xr.x, ai0));
                ar1 = fmaf(cs.x, xr.y, fmaf( cs.y, xi.y, ar1));
                ai1 = fmaf(cs.x, xi.y, fmaf(-cs.y, xr.y, ai1));
                ar2 = fmaf(cs.x, xr.z, fmaf( cs.y, xi.z, ar2));
                ai2 = fmaf(cs.x, xi.z, fmaf(-cs.y, xr.z, ai2));
                ar3 = fmaf(cs.x, xr.w, fmaf( cs.y, xi.w, ar3));
                ai3 = fmaf(cs.x, xi.w, fmaf(-cs.y, xr.w, ai3));
            } else {      // re += c*Xr - s*Xi ; im += c*Xi + s*Xr
                ar0 = fmaf(cs.x, xr.x, fmaf(-cs.y, xi.x, ar0));
                ai0 = fmaf(cs.x, xi.x, fmaf( cs.y, xr.x, ai0));
                ar1 = fmaf(cs.x, xr.y, fmaf(-cs.y, xi.y, ar1));
                ai1 = fmaf(cs.x, xi.y, fmaf( cs.y, xr.y, ai1));
                ar2 = fmaf(cs.x, xr.z, fmaf(-cs.y, xi.z, ar2));
                ai2 = fmaf(cs.x, xi.z, fmaf( cs.y, xr.z, ai2));
                ar3 = fmaf(cs.x, xr.w, fmaf(-cs.y, xi.w, ar3));
                ai3 = fmaf(cs.x, xi.w, fmaf( cs.y, xr.w, ai3));
            }
        }
        const int ab = cbase + h * NY + y0 + g;
        if (g + 0 < ylen) { fre[ab + 0] = ar0; fim[ab + 0] = ai0; }
        if (g + 1 < ylen) { fre[ab + 1] = ar1; fim[ab + 1] = ai1; }
        if (g + 2 < ylen) { fre[ab + 2] = ar2; fim[ab + 2] = ai2; }
        if (g + 3 < ylen) { fre[ab + 3] = ar3; fim[ab + 3] = ai3; }
    }
}

__device__ __forceinline__ float sshrink(float v) {
    return (v > LAM) ? (v - LAM) : ((v < -LAM) ? (v + LAM) : 0.f);
}

// ---------------------------------------------------------------------------
// Stage C: per-mode block-diagonal complex MLP, in place.
// One block = (k, tile of 8 modes). 192 threads: thread = (o in [0,96), mode-group 0/1).
__global__ __launch_bounds__(192) void kC(const float* __restrict__ w1,
                                          const float* __restrict__ b1,
                                          const float* __restrict__ w2,
                                          const float* __restrict__ b2,
                                          float* __restrict__ fre,
                                          float* __restrict__ fim) {
    __shared__ __align__(16) float Ar[BSZ][8], Ai[BSZ][8], Or[BSZ][8], Oi[BSZ][8];
    const int tid = threadIdx.x;
    const int k   = blockIdx.y;
    const int m0  = blockIdx.x * 8;
    for (int t = tid; t < BSZ * 8; t += 192) {
        const int i = t >> 3, m = t & 7;
        const int mm = m0 + m;
        float vr = 0.f, vi = 0.f;
        if (mm < NMODE) {
            const int a = (k * BSZ + i) * NMODE + mm;
            vr = fre[a]; vi = fim[a];
        }
        Ar[i][m] = vr; Ai[i][m] = vi;
    }
    __syncthreads();
    const int o = (tid >= BSZ) ? tid - BSZ : tid;
    const int g = (tid >= BSZ) ? 4 : 0;
    const float* w1k = w1 + k * BSZ * BSZ * 2;
    const float* w2k = w2 + k * BSZ * BSZ * 2;

    float r0=0.f,r1=0.f,r2=0.f,r3=0.f, s0=0.f,s1=0.f,s2=0.f,s3=0.f;
    for (int i = 0; i < BSZ; ++i) {
        const float2 wv = *(const float2*)(w1k + ((i * BSZ + o) << 1));
        const float4 xr = *(const float4*)&Ar[i][g];
        const float4 xi = *(const float4*)&Ai[i][g];
        r0 = fmaf(xr.x, wv.x, fmaf(-xi.x, wv.y, r0));
        s0 = fmaf(xi.x, wv.x, fmaf( xr.x, wv.y, s0));
        r1 = fmaf(xr.y, wv.x, fmaf(-xi.y, wv.y, r1));
        s1 = fmaf(xi.y, wv.x, fmaf( xr.y, wv.y, s1));
        r2 = fmaf(xr.z, wv.x, fmaf(-xi.z, wv.y, r2));
        s2 = fmaf(xi.z, wv.x, fmaf( xr.z, wv.y, s2));
        r3 = fmaf(xr.w, wv.x, fmaf(-xi.w, wv.y, r3));
        s3 = fmaf(xi.w, wv.x, fmaf( xr.w, wv.y, s3));
    }
    const float2 bv1 = *(const float2*)(b1 + (k * BSZ + o) * 2);
    r0 = fmaxf(r0 + bv1.x, 0.f); s0 = fmaxf(s0 + bv1.y, 0.f);
    r1 = fmaxf(r1 + bv1.x, 0.f); s1 = fmaxf(s1 + bv1.y, 0.f);
    r2 = fmaxf(r2 + bv1.x, 0.f); s2 = fmaxf(s2 + bv1.y, 0.f);
    r3 = fmaxf(r3 + bv1.x, 0.f); s3 = fmaxf(s3 + bv1.y, 0.f);
    *(float4*)&Or[o][g] = make_float4(r0, r1, r2, r3);
    *(float4*)&Oi[o][g] = make_float4(s0, s1, s2, s3);
    __syncthreads();

    r0=0.f;r1=0.f;r2=0.f;r3=0.f; s0=0.f;s1=0.f;s2=0.f;s3=0.f;
    for (int i = 0; i < BSZ; ++i) {
        const float2 wv = *(const float2*)(w2k + ((i * BSZ + o) << 1));
        const float4 xr = *(const float4*)&Or[i][g];
        const float4 xi = *(const float4*)&Oi[i][g];
        r0 = fmaf(xr.x, wv.x, fmaf(-xi.x, wv.y, r0));
        s0 = fmaf(xi.x, wv.x, fmaf( xr.x, wv.y, s0));
        r1 = fmaf(xr.y, wv.x, fmaf(-xi.y, wv.y, r1));
        s1 = fmaf(xi.y, wv.x, fmaf( xr.y, wv.y, s1));
        r2 = fmaf(xr.z, wv.x, fmaf(-xi.z, wv.y, r2));
        s2 = fmaf(xi.z, wv.x, fmaf( xr.z, wv.y, s2));
        r3 = fmaf(xr.w, wv.x, fmaf(-xi.w, wv.y, r3));
        s3 = fmaf(xi.w, wv.x, fmaf( xr.w, wv.y, s3));
    }
    const float2 bv2 = *(const float2*)(b2 + (k * BSZ + o) * 2);
    const int crow = (k * BSZ + o) * NMODE;
    {
        const int mm = m0 + g + 0;
        if (mm < NMODE) { fre[crow+mm] = sshrink(r0+bv2.x); fim[crow+mm] = sshrink(s0+bv2.y); }
    }
    {
        const int mm = m0 + g + 1;
        if (mm < NMODE) { fre[crow+mm] = sshrink(r1+bv2.x); fim[crow+mm] = sshrink(s1+bv2.y); }
    }
    {
        const int mm = m0 + g + 2;
        if (mm < NMODE) { fre[crow+mm] = sshrink(r2+bv2.x); fim[crow+mm] = sshrink(s2+bv2.y); }
    }
    {
        const int mm = m0 + g + 3;
        if (mm < NMODE) { fre[crow+mm] = sshrink(r3+bv2.x); fim[crow+mm] = sshrink(s3+bv2.y); }
    }
}

// ---------------------------------------------------------------------------
// Stage E: inverse real DFT along W (91 nonzero bins -> 360 reals) + residual.
// pocketfft c2r semantics: imag of bin 0 ignored; bins 91..180 are zero.
__global__ __launch_bounds__(256) void kE(const float* __restrict__ x,
                                          const float* __restrict__ fre,
                                          const float* __restrict__ fim,
                                          float* __restrict__ out) {
    __shared__ __align__(16) float yr[NY][36], yi[NY][36];
    __shared__ float2 tw[WDIM];
    const int tid  = threadIdx.x;
    const int row0 = blockIdx.x * 32;
    const int fb   = row0 * NY;
    for (int t = tid; t < 32 * NY; t += 256) {
        const int r = t / NY;
        const int y = t - r * NY;
        yr[y][r] = fre[fb + t];
        yi[y][r] = fim[fb + t];
    }
    for (int j = tid; j < WDIM; j += 256) {
        float sv, cv;
        sincosf(0.017453292519943295f * (float)j, &sv, &cv);
        tw[j] = make_float2(cv, sv);
    }
    __syncthreads();
    for (int t = tid; t < WDIM * 8; t += 256) {
        const int w = t >> 3;
        const int g = (t & 7) << 2;
        float a0=0.f,a1=0.f,a2=0.f,a3=0.f;
        int idx = w;                          // (k*w) mod 360 starting at k=1
        for (int kk = 1; kk < NY; ++kk) {
            const float2 cs = tw[idx];
            idx += w; if (idx >= WDIM) idx -= WDIM;
            const float4 vr = *(const float4*)&yr[kk][g];
            const float4 vi = *(const float4*)&yi[kk][g];
            // 2*Re(Y e^{+i t})/2 = Yr*cos - Yi*sin  (factor 2 applied at store)
            a0 = fmaf(vr.x, cs.x, fmaf(-vi.x, cs.y, a0));
            a1 = fmaf(vr.y, cs.x, fmaf(-vi.y, cs.y, a1));
            a2 = fmaf(vr.z, cs.x, fmaf(-vi.z, cs.y, a2));
            a3 = fmaf(vr.w, cs.x, fmaf(-vi.w, cs.y, a3));
        }
        const float4 v0 = *(const float4*)&yr[0][g];
        int oa = (row0 + g) * WDIM + w;
        out[oa] = x[oa] + ORTHO * (v0.x + 2.f * a0); oa += WDIM;
        out[oa] = x[oa] + ORTHO * (v0.y + 2.f * a1); oa += WDIM;
        out[oa] = x[oa] + ORTHO * (v0.z + 2.f * a2); oa += WDIM;
        out[oa] = x[oa] + ORTHO * (v0.w + 2.f * a3);
    }
}

// ---------------------------------------------------------------------------
extern "C" void kernel_launch(void* const* d_in, const int* in_sizes, int n_in,
                              void* d_out, int out_size, void* d_ws, size_t ws_size,
                              hipStream_t stream) {
    const float* x  = (const float*)d_in[0];
    const float* w1 = (const float*)d_in[1];
    const float* b1 = (const float*)d_in[2];
    const float* w2 = (const float*)d_in[3];
    const float* b2 = (const float*)d_in[4];
    float* out = (float*)d_out;

    float* fre = (float*)d_ws;                       // 768*180*91 floats
    float* fim = fre + (size_t)CCH * NMODE;          // second plane

    const int nrowblk = (CCH * HDIM) / 32;           // 4320
    hipLaunchKernelGGL(kA, dim3(nrowblk), dim3(256), 0, stream, x, fre, fim);
    hipLaunchKernelGGL((kH<0>), dim3(CCH, 3), dim3(256), 0, stream, fre, fim);
    hipLaunchKernelGGL(kC, dim3((NMODE + 7) / 8, 8), dim3(192), 0, stream,
                       w1, b1, w2, b2, fre, fim);
    hipLaunchKernelGGL((kH<1>), dim3(CCH, 3), dim3(256), 0, stream, fre, fim);
    hipLaunchKernelGGL(kE, dim3(nrowblk), dim3(256), 0, stream, x, fre, fim, out);
}

// Round 2
// 937.614 us; speedup vs baseline: 2.3116x; 2.3116x over previous
//
#include <hip/hip_runtime.h>
#include <math.h>

// ---------------------------------------------------------------------------
// AFNO2D as 5 bf16-MFMA GEMM stages + constant bake.
//   x:[1,768,180,360] f32. rfft2(ortho) -> per-mode blockdiag complex MLP
//   (8 blocks x 96ch, relu, softshrink, W-modes y<91 kept) -> irfft2 + x.
//
// GEMM forms (D = A*B, mfma_f32_16x16x32_bf16):
//  gA : per (c, h-half): D[m=h(96)][n=(s*96+y)(192)] = x-rows(K=384) * BA
//       store transposed -> G1[c][y][s*180+h]        (regs = 4 consecutive h)
//  gHf: per c: D[m=(s*192+h')(384)][n=y(96)] = BH(A) * G1-rows(B, K=384)
//       store -> F2[c2=2c+s][y*180+h']               (regs = 4 consecutive h')
//  gC : per (kb, 64-mode tile): Act(LDS-transposed from F2) * BW1 -> relu
//       -> *BW2 -> softshrink, store -> F3[cout][y][s'*180+h'] (4 consec h')
//  gHi: per c: D[m=y(96)][n=(s*192+h)(384)] = F3-rows(A) * BHI(B)
//       store -> Spec[(c*180+h)][s*96+y]             (regs = 4 consecutive y)
//  gE : per 64-row tile: D[m=row][n=w(368)] = Spec-rows(A, K=192) * BE
//       out = x + D (fp32)
// Fragment layouts used (guide-verified): A[m=l&15][k=q*8+j],
// B[k=q*8+j][n=l&15], C/D[row=q*4+reg][col=l&15].
// ---------------------------------------------------------------------------

#define R360f 0.05270462766947299f   // 1/sqrt(360)
#define R180f 0.07453559924999299f   // 1/sqrt(180)
#define LAM   0.01f

typedef short v8s __attribute__((ext_vector_type(8)));
typedef float v4f __attribute__((ext_vector_type(4)));

#define MFMA(a,b,c) __builtin_amdgcn_mfma_f32_16x16x32_bf16(a,b,c,0,0,0)

// ws layout (shorts): BUF1 | BUF2 | BA | BH | BHI | BW1 | BW2 | BE
#define NBUF  26542080              // 53,084,160 B per ping-pong buffer
#define OBA   (2*NBUF)
#define OBH   (OBA + 73728)         // BA  [192][384]
#define OBHI  (OBH + 147456)        // BH  [384][384]
#define OBW1  (OBHI + 147456)       // BHI [384][384]
#define OBW2  (OBW1 + 294912)       // BW1 [8][192][192]
#define OBE   (OBW2 + 294912)       // BW2 [8][192][192]
#define NBAKE 1032192               // + BE [384][192]

static __device__ __forceinline__ short f2bs(float f){   // f32 -> bf16 (RNE)
    unsigned u = __builtin_bit_cast(unsigned, f);
    u = (u + 0x7fffu + ((u >> 16) & 1u)) >> 16;
    return (short)u;
}
static __device__ __forceinline__ v8s ld8(const short* p){
    return __builtin_bit_cast(v8s, *(const uint4*)p);
}
union PK { short s[4]; uint2 u; };
static __device__ __forceinline__ uint2 pk4(v4f a){
    PK t; t.s[0]=f2bs(a[0]); t.s[1]=f2bs(a[1]); t.s[2]=f2bs(a[2]); t.s[3]=f2bs(a[3]);
    return t.u;
}
union S8 { uint4 u; short s[8]; v8s v; };
static __device__ __forceinline__ float sshrink(float v){
    return (v > LAM) ? (v - LAM) : ((v < -LAM) ? (v + LAM) : 0.f);
}

// ---------------------------------------------------------------------------
__global__ __launch_bounds__(256) void bake(const float* __restrict__ w1,
                                            const float* __restrict__ w2,
                                            short* __restrict__ bt){
    int idx = blockIdx.x*256 + threadIdx.x;
    if (idx >= NBAKE) return;
    float v = 0.f;
    if (idx < 73728){                               // BA (B-role) [n=s*96+y][k=w]
        int n = idx/384, k = idx - n*384;
        int s = n >= 96, y = n - s*96;
        if (y < 91 && k < 360){
            float th = (float)((k*y) % 360) * 0.017453292519943295f;
            float sv, cv; sincosf(th, &sv, &cv);
            v = s ? -sv*R360f : cv*R360f;           // e^{-i th}
        }
        bt[OBA + idx] = f2bs(v); return;
    }
    idx -= 73728;
    if (idx < 147456){                              // BH (A-role) [m=s*192+h'][k=si*180+h]
        int m = idx/384, k = idx - m*384;
        int s = m >= 192, hp = m - s*192;
        if (hp < 180 && k < 360){
            int si = k >= 180; int h = k - si*180;
            float th = (float)((h*hp) % 180) * 0.03490658503988659f;
            float sv, cv; sincosf(th, &sv, &cv);
            v = R180f * (s == 0 ? (si == 0 ? cv : sv) : (si == 0 ? -sv : cv));
        }
        bt[OBH + idx] = f2bs(v); return;
    }
    idx -= 147456;
    if (idx < 147456){                              // BHI (B-role) [n=s*192+h][k=sp*180+h']
        int n = idx/384, k = idx - n*384;
        int s = n >= 192, h = n - s*192;
        if (h < 180 && k < 360){
            int sp = k >= 180; int hp = k - sp*180;
            float th = (float)((h*hp) % 180) * 0.03490658503988659f;
            float sv, cv; sincosf(th, &sv, &cv);
            v = R180f * (s == 0 ? (sp == 0 ? cv : -sv) : (sp == 0 ? sv : cv));
        }
        bt[OBHI + idx] = f2bs(v); return;
    }
    idx -= 147456;
    if (idx < 294912){                              // BW1 (B-role) [kb][n=2o+sp][k=2i+si]
        int kb = idx / 36864; int r = idx - kb*36864;
        int n = r / 192, k = r - n*192;
        int o = n >> 1, sp = n & 1, i = k >> 1, si = k & 1;
        const float* wp = w1 + ((((kb*96 + i)*96) + o) << 1);
        v = sp == 0 ? (si == 0 ? wp[0] : -wp[1]) : (si == 0 ? wp[1] : wp[0]);
        bt[OBW1 + idx] = f2bs(v); return;
    }
    idx -= 294912;
    if (idx < 294912){                              // BW2
        int kb = idx / 36864; int r = idx - kb*36864;
        int n = r / 192, k = r - n*192;
        int o = n >> 1, sp = n & 1, i = k >> 1, si = k & 1;
        const float* wp = w2 + ((((kb*96 + i)*96) + o) << 1);
        v = sp == 0 ? (si == 0 ? wp[0] : -wp[1]) : (si == 0 ? wp[1] : wp[0]);
        bt[OBW2 + idx] = f2bs(v); return;
    }
    idx -= 294912;
    {                                               // BE (B-role) [n=w][k=s*96+y]
        int w = idx / 192, k = idx - w*192;
        int s = k >= 96, y = k - s*96;
        if (w < 360 && y < 91){
            float th = (float)((y*w) % 360) * 0.017453292519943295f;
            float sv, cv; sincosf(th, &sv, &cv);
            v = (s == 0) ? (y == 0 ? 1.f : 2.f) * cv * R360f
                         : (y == 0 ? 0.f : -2.f*sv*R360f);
        }
        bt[OBE + idx] = f2bs(v);
    }
}

// ---------------------------------------------------------------------------
__global__ __launch_bounds__(256) void gA(const float* __restrict__ x,
                                          short* __restrict__ G1,
                                          const short* __restrict__ BA){
    const int b = blockIdx.x, c = b >> 1, hh = (b & 1)*96;
    const int tid = threadIdx.x, wid = tid >> 6, lane = tid & 63;
    const int l15 = lane & 15, q8 = (lane >> 4) << 3, q4 = q8 >> 1;
    const int nt0 = wid*3;
    const v4f vz = {0.f,0.f,0.f,0.f};
    v4f acc[6][3];
    #pragma unroll
    for (int i=0;i<6;++i){ acc[i][0]=vz; acc[i][1]=vz; acc[i][2]=vz; }
    for (int ks=0; ks<12; ++ks){
        const int k0 = ks*32;
        int kk = k0 + q8; if (kk >= 360) kk = 0;   // garbage * zero B-rows
        v8s af[6];
        #pragma unroll
        for (int mt=0; mt<6; ++mt){
            int h = hh + mt*16 + l15; if (h > 179) h = 179;  // rows>=180 dropped at store
            const float* xp = x + (c*180 + h)*360 + kk;
            float4 f0 = *(const float4*)xp;
            float4 f1 = *(const float4*)(xp + 4);
            S8 tt;
            tt.s[0]=f2bs(f0.x); tt.s[1]=f2bs(f0.y); tt.s[2]=f2bs(f0.z); tt.s[3]=f2bs(f0.w);
            tt.s[4]=f2bs(f1.x); tt.s[5]=f2bs(f1.y); tt.s[6]=f2bs(f1.z); tt.s[7]=f2bs(f1.w);
            af[mt] = tt.v;
        }
        v8s bf[3];
        #pragma unroll
        for (int j=0;j<3;++j)
            bf[j] = ld8(BA + ((nt0+j)*16 + l15)*384 + k0 + q8);
        #pragma unroll
        for (int mt=0; mt<6; ++mt)
            #pragma unroll
            for (int j=0;j<3;++j)
                acc[mt][j] = MFMA(af[mt], bf[j], acc[mt][j]);
    }
    #pragma unroll
    for (int mt=0; mt<6; ++mt){
        int hg = hh + mt*16 + q4;                   // 4-aligned, never straddles 180
        if (hg >= 180) continue;
        #pragma unroll
        for (int j=0;j<3;++j){
            int n = (nt0+j)*16 + l15;
            int s = n >= 96, y = n - s*96;
            *(uint2*)(G1 + (c*96 + y)*360 + s*180 + hg) = pk4(acc[mt][j]);
        }
    }
}

// ---------------------------------------------------------------------------
__global__ __launch_bounds__(512) void gHf(const short* __restrict__ G1,
                                           short* __restrict__ F2,
                                           const short* __restrict__ BH){
    const int c = blockIdx.x;
    const int tid = threadIdx.x, wid = tid >> 6, lane = tid & 63;
    const int l15 = lane & 15, q8 = (lane >> 4) << 3, q4 = q8 >> 1;
    const int mt0 = wid*3;
    const v4f vz = {0.f,0.f,0.f,0.f};
    v4f acc[3][6];
    #pragma unroll
    for (int i=0;i<3;++i)
        #pragma unroll
        for (int j=0;j<6;++j) acc[i][j]=vz;
    for (int ks=0; ks<12; ++ks){
        const int k0 = ks*32;
        int kk = k0 + q8; if (kk >= 360) kk = 0;
        v8s af[3];
        #pragma unroll
        for (int i=0;i<3;++i)
            af[i] = ld8(BH + ((mt0+i)*16 + l15)*384 + k0 + q8);
        v8s bf[6];
        #pragma unroll
        for (int j=0;j<6;++j)
            bf[j] = ld8(G1 + (c*96 + j*16 + l15)*360 + kk);
        #pragma unroll
        for (int i=0;i<3;++i)
            #pragma unroll
            for (int j=0;j<6;++j)
                acc[i][j] = MFMA(af[i], bf[j], acc[i][j]);
    }
    #pragma unroll
    for (int i=0;i<3;++i){
        int m = (mt0+i)*16 + q4;
        int s = m >= 192, hp = m - s*192;
        if (hp >= 180) continue;
        const int rb = (2*c + s)*17280 + hp;
        #pragma unroll
        for (int j=0;j<6;++j){
            int y = j*16 + l15;
            *(uint2*)(F2 + rb + y*180) = pk4(acc[i][j]);
        }
    }
}

// ---------------------------------------------------------------------------
__global__ __launch_bounds__(256) void gC(const short* __restrict__ F2,
                                          short* __restrict__ F3,
                                          const short* __restrict__ BW1,
                                          const short* __restrict__ BW2,
                                          const float* __restrict__ b1,
                                          const float* __restrict__ b2){
    __shared__ short Act[64*200];    // [mode 64][ch2 192 + 8 pad]
    __shared__ short O1[64*200];
    const int mt = blockIdx.x, kb = blockIdx.y, m0 = mt*64;
    const int tid = threadIdx.x;
    #pragma unroll
    for (int i=0;i<6;++i){           // 1536 16B-chunks: transpose F2 -> Act
        int ch = tid + 256*i;
        int qq = ch / 192, rr = ch - qq*192;
        S8 tt; tt.u = *(const uint4*)(F2 + (kb*192 + rr)*17280 + m0 + qq*8);
        #pragma unroll
        for (int j=0;j<8;++j) Act[(qq*8+j)*200 + rr] = tt.s[j];  // consec lanes -> consec elems
    }
    __syncthreads();
    const int wid = tid >> 6, lane = tid & 63, l15 = lane & 15;
    const int q8 = (lane >> 4) << 3, q4 = q8 >> 1;
    const short* bw1 = BW1 + kb*36864;
    const short* bw2 = BW2 + kb*36864;
    const v4f vz = {0.f,0.f,0.f,0.f};
    v4f a1[12];
    #pragma unroll
    for (int nt=0; nt<12; ++nt) a1[nt]=vz;
    for (int ks=0; ks<6; ++ks){
        int k0 = ks*32;
        v8s af = __builtin_bit_cast(v8s, *(const uint4*)(Act + (wid*16 + l15)*200 + k0 + q8));
        #pragma unroll
        for (int nt=0; nt<12; ++nt)
            a1[nt] = MFMA(af, ld8(bw1 + (nt*16 + l15)*192 + k0 + q8), a1[nt]);
    }
    #pragma unroll
    for (int nt=0; nt<12; ++nt){
        int n = nt*16 + l15;
        float bv = b1[(kb*96 + (n>>1))*2 + (n&1)];
        #pragma unroll
        for (int r=0;r<4;++r)
            O1[(wid*16 + q4 + r)*200 + n] = f2bs(fmaxf(a1[nt][r] + bv, 0.f));
    }
    // wave w wrote exactly rows [w*16, w*16+16) and reads only those: no barrier.
    v4f a2[12];
    #pragma unroll
    for (int nt=0; nt<12; ++nt) a2[nt]=vz;
    for (int ks=0; ks<6; ++ks){
        int k0 = ks*32;
        v8s af = __builtin_bit_cast(v8s, *(const uint4*)(O1 + (wid*16 + l15)*200 + k0 + q8));
        #pragma unroll
        for (int nt=0; nt<12; ++nt)
            a2[nt] = MFMA(af, ld8(bw2 + (nt*16 + l15)*192 + k0 + q8), a2[nt]);
    }
    const int mb = m0 + wid*16 + q4;                // 4-aligned, never straddles 180
    const int y = mb / 180, hp = mb - y*180;
    #pragma unroll
    for (int nt=0; nt<12; ++nt){
        int n = nt*16 + l15;
        int o = n >> 1, sp = n & 1;
        float bv = b2[(kb*96 + o)*2 + sp];
        v4f vv;
        #pragma unroll
        for (int r=0;r<4;++r) vv[r] = sshrink(a2[nt][r] + bv);
        *(uint2*)(F3 + ((kb*96 + o)*96 + y)*360 + sp*180 + hp) = pk4(vv);
    }
}

// ---------------------------------------------------------------------------
__global__ __launch_bounds__(512) void gHi(const short* __restrict__ F3,
                                           short* __restrict__ Sp,
                                           const short* __restrict__ BHI){
    const int c = blockIdx.x;
    const int tid = threadIdx.x, wid = tid >> 6, lane = tid & 63;
    const int l15 = lane & 15, q8 = (lane >> 4) << 3, q4 = q8 >> 1;
    const int nt0 = wid*3;
    const v4f vz = {0.f,0.f,0.f,0.f};
    v4f acc[6][3];
    #pragma unroll
    for (int i=0;i<6;++i){ acc[i][0]=vz; acc[i][1]=vz; acc[i][2]=vz; }
    for (int ks=0; ks<12; ++ks){
        const int k0 = ks*32;
        int kk = k0 + q8; if (kk >= 360) kk = 0;
        v8s af[6];
        #pragma unroll
        for (int i=0;i<6;++i)
            af[i] = ld8(F3 + (c*96 + i*16 + l15)*360 + kk);
        v8s bf[3];
        #pragma unroll
        for (int j=0;j<3;++j)
            bf[j] = ld8(BHI + ((nt0+j)*16 + l15)*384 + k0 + q8);
        #pragma unroll
        for (int i=0;i<6;++i)
            #pragma unroll
            for (int j=0;j<3;++j)
                acc[i][j] = MFMA(af[i], bf[j], acc[i][j]);
    }
    #pragma unroll
    for (int j=0;j<3;++j){
        int n = (nt0+j)*16 + l15;
        int s = n >= 192, h = n - s*192;
        if (h >= 180) continue;
        const int rb = (c*180 + h)*192 + s*96;
        #pragma unroll
        for (int i=0;i<6;++i)
            *(uint2*)(Sp + rb + i*16 + q4) = pk4(acc[i][j]);
    }
}

// ---------------------------------------------------------------------------
__global__ __launch_bounds__(256) void gE(const float* __restrict__ x,
                                          const short* __restrict__ Sp,
                                          const short* __restrict__ BE,
                                          float* __restrict__ out){
    const int b = blockIdx.x;
    const int tid = threadIdx.x, wid = tid >> 6, lane = tid & 63;
    const int l15 = lane & 15, q8 = (lane >> 4) << 3, q4 = q8 >> 1;
    const int row = b*64 + wid*16;
    const v4f vz = {0.f,0.f,0.f,0.f};
    v4f acc[23];
    #pragma unroll
    for (int nt=0; nt<23; ++nt) acc[nt]=vz;
    const short* ar = Sp + (row + l15)*192;
    for (int ks=0; ks<6; ++ks){
        int k0 = ks*32;
        v8s af = ld8(ar + k0 + q8);
        #pragma unroll
        for (int nt=0; nt<23; ++nt)
            acc[nt] = MFMA(af, ld8(BE + (nt*16 + l15)*192 + k0 + q8), acc[nt]);
    }
    #pragma unroll
    for (int nt=0; nt<23; ++nt){
        int w = nt*16 + l15;
        if (w < 360){
            #pragma unroll
            for (int r=0;r<4;++r){
                int a = (row + q4 + r)*360 + w;
                out[a] = x[a] + acc[nt][r];
            }
        }
    }
}

// ---------------------------------------------------------------------------
extern "C" void kernel_launch(void* const* d_in, const int* in_sizes, int n_in,
                              void* d_out, int out_size, void* d_ws, size_t ws_size,
                              hipStream_t stream){
    const float* x  = (const float*)d_in[0];
    const float* w1 = (const float*)d_in[1];
    const float* b1 = (const float*)d_in[2];
    const float* w2 = (const float*)d_in[3];
    const float* b2 = (const float*)d_in[4];
    float* out = (float*)d_out;
    short* ws = (short*)d_ws;
    short* B1 = ws;              // G1 then F3 (53.08 MB)
    short* B2 = ws + NBUF;       // F2 then Spec (53.08 MB)

    hipLaunchKernelGGL(bake, dim3((NBAKE+255)/256), dim3(256), 0, stream, w1, w2, ws);
    hipLaunchKernelGGL(gA,  dim3(1536),    dim3(256), 0, stream, x, B1, ws + OBA);
    hipLaunchKernelGGL(gHf, dim3(768),     dim3(512), 0, stream, B1, B2, ws + OBH);
    hipLaunchKernelGGL(gC,  dim3(270, 8),  dim3(256), 0, stream, B2, B1,
                       ws + OBW1, ws + OBW2, b1, b2);
    hipLaunchKernelGGL(gHi, dim3(768),     dim3(512), 0, stream, B1, B2, ws + OBHI);
    hipLaunchKernelGGL(gE,  dim3(2160),    dim3(256), 0, stream, x, B2, ws + OBE, out);
}